// Round 20
// baseline (344.926 us; speedup 1.0000x reference)
//
#include <hip/hip_runtime.h>
#include <hip/hip_bf16.h>

typedef __hip_bfloat16 bf16;
typedef __attribute__((ext_vector_type(8))) short s8v;   // 8 bf16 (4 VGPRs)
typedef __attribute__((ext_vector_type(4))) float f4v;   // 4 fp32 acc

#define NN 32768   // total nodes
#define EE 262144  // edges
#define GG 512     // graphs
#define LDW 520    // padded LDS row stride (bf16 elems)

__device__ __forceinline__ float2 unpk(unsigned u) {
  float2 r;
  r.x = __uint_as_float(u << 16);
  r.y = __uint_as_float(u & 0xffff0000u);
  return r;
}
__device__ __forceinline__ unsigned pk(float x, float y) {
  union { bf16 h[2]; unsigned u; } p;
  p.h[0] = __float2bfloat16(x);
  p.h[1] = __float2bfloat16(y);
  return p.u;
}
__device__ __forceinline__ short f2bf_bits(float x) {
  bf16 h = __float2bfloat16(x);
  return *reinterpret_cast<short*>(&h);
}
__device__ __forceinline__ void storef(float* p, float v) { *p = v; }
__device__ __forceinline__ void storef(bf16* p, float v) { *p = __float2bfloat16(v); }

__device__ __forceinline__ float wred_sum(float v) {
#pragma unroll
  for (int o = 32; o; o >>= 1) v += __shfl_xor(v, o, 64);
  return v;
}

// ---------------- CSR build ----------------
__global__ __launch_bounds__(256) void hist_kernel(const int* __restrict__ dst,
                                                   int* __restrict__ indeg) {
  int e = blockIdx.x * 256 + threadIdx.x;
  if (e < EE) atomicAdd(&indeg[dst[e]], 1);
}

__global__ __launch_bounds__(1024) void scan_kernel(const int* __restrict__ indeg,
                                                    int* __restrict__ off,
                                                    int* __restrict__ cursor) {
  __shared__ int sh[1024];
  int t = threadIdx.x;
  int loc[32];
  int s = 0;
  int base = t * 32;
#pragma unroll
  for (int j = 0; j < 32; j++) { loc[j] = indeg[base + j]; s += loc[j]; }
  sh[t] = s;
  __syncthreads();
  for (int d = 1; d < 1024; d <<= 1) {
    int v = (t >= d) ? sh[t - d] : 0;
    __syncthreads();
    sh[t] += v;
    __syncthreads();
  }
  int run = (t == 0) ? 0 : sh[t - 1];
#pragma unroll
  for (int j = 0; j < 32; j++) { off[base + j] = run; cursor[base + j] = run; run += loc[j]; }
  if (t == 1023) off[NN] = run;
}

__global__ __launch_bounds__(256) void fill_kernel(const int* __restrict__ src,
                                                   const int* __restrict__ dst,
                                                   int* __restrict__ cursor,
                                                   int* __restrict__ esrc) {
  int e = blockIdx.x * 256 + threadIdx.x;
  if (e < EE) {
    int p = atomicAdd(&cursor[dst[e]], 1);
    esrc[p] = src[e];
  }
}

// ---------------- fp32 -> packed bf16 conversion (t and v in one launch) ----------------
__global__ __launch_bounds__(256) void cvtpk2_kernel(const float2* __restrict__ a,
                                                     unsigned* __restrict__ da,
                                                     const float2* __restrict__ b,
                                                     unsigned* __restrict__ db, int n2) {
  int id = blockIdx.x * 256 + threadIdx.x;
  if (id < n2) { float2 v = a[id]; da[id] = pk(v.x, v.y); }
  else if (id < 2 * n2) { int j = id - n2; float2 v = b[j]; db[j] = pk(v.x, v.y); }
}

// ---------------- small GEMM, split-K (tiny problems) ----------------
template <typename TC>
__global__ __launch_bounds__(256) void sgemm_kernel(const float* __restrict__ A,
                                                    const float* __restrict__ B,
                                                    const float* __restrict__ bias,
                                                    TC* __restrict__ C,
                                                    int M, int N, int K, int ldc, int act) {
  __shared__ float red[256];
  int tid = threadIdx.x;
  int lo = tid & 63;
  int slice = tid >> 6;
  long oid = (long)blockIdx.x * 64 + lo;
  bool live = (oid < (long)M * N);
  int m = 0, n = 0;
  if (live) { m = (int)(oid / N); n = (int)(oid % N); }
  int kq = K >> 2;
  int k0 = slice * kq, k1 = k0 + kq;
  float acc = 0.f;
  if (live) {
    const float* Ar = A + (size_t)m * K;
    for (int k = k0; k < k1; k++) acc = fmaf(Ar[k], B[(size_t)k * N + n], acc);
  }
  red[tid] = acc;
  __syncthreads();
  if (slice == 0 && live) {
    float v = red[lo] + red[64 + lo] + red[128 + lo] + red[192 + lo];
    if (bias) v += bias[n];
    if (act == 1) v = v > 0.f ? v : 0.01f * v;
    storef(&C[(size_t)m * ldc + n], v);
  }
}

// ---------------- pack all 5 weights into MFMA B-fragment order, one launch ----------------
__device__ __forceinline__ void packB_one(const float* W, int N, int K, int id, s8v* Bp) {
  int lane = id & 63;
  int tmp = id >> 6;
  int ksteps = K >> 5;
  int ks = tmp % ksteps;
  int nt = tmp / ksteps;
  int n = nt * 16 + (lane & 15);
  int kbase = ks * 32 + (lane >> 4) * 8;
  s8v r;
#pragma unroll
  for (int j = 0; j < 8; j++) r[j] = f2bf_bits(W[(size_t)(kbase + j) * N + n]);
  Bp[id] = r;
}

__global__ __launch_bounds__(256) void packall_kernel(const float* __restrict__ W1, s8v* Bp1,
                                                      const float* __restrict__ W2, s8v* Bp2,
                                                      const float* __restrict__ Wv, s8v* BpWv,
                                                      const float* __restrict__ Wt, s8v* BpWt,
                                                      const float* __restrict__ Ws, s8v* BpWs) {
  int b = blockIdx.x;
  if (b < 32)        packB_one(W1, 512, 128, b * 256 + threadIdx.x, Bp1);
  else if (b < 64)   packB_one(W2, 128, 512, (b - 32) * 256 + threadIdx.x, Bp2);
  else if (b < 112)  packB_one(Wv, 128, 768, (b - 64) * 256 + threadIdx.x, BpWv);
  else if (b < 160)  packB_one(Wt, 128, 768, (b - 112) * 256 + threadIdx.x, BpWt);
  else               packB_one(Ws, 128, 256, (b - 160) * 256 + threadIdx.x, BpWs);
}

// ---------------- fold a_src/a_dst through W1 ----------------
__global__ __launch_bounds__(256) void fold1_kernel(const float* __restrict__ W1,
                                                    const float* __restrict__ a_src1,
                                                    const float* __restrict__ a_dst1,
                                                    float* __restrict__ ws1,
                                                    float* __restrict__ wd1) {
  int id = blockIdx.x * 256 + threadIdx.x;
  if (id >= 512) return;
  int h = id >> 7, k = id & 127;
  float s = 0.f, d = 0.f;
  for (int c = 0; c < 128; c++) {
    float w = W1[(size_t)k * 512 + h * 128 + c];
    s = fmaf(w, a_src1[h * 128 + c], s);
    d = fmaf(w, a_dst1[h * 128 + c], d);
  }
  ws1[id] = s;
  wd1[id] = d;
}

// ---------------- MFMA bf16 GEMM, optional fp32 bias, bf16 out with ldc ----------------
__global__ __launch_bounds__(256) void gemm_mfma(const short* __restrict__ A,
                                                 const s8v* __restrict__ Bp,
                                                 const float* __restrict__ bias,
                                                 short* __restrict__ C,
                                                 int M, int N, int K, int ldc) {
  __shared__ short lds[64 * 64];
  int tid = threadIdx.x;
  int wv = tid >> 6, lane = tid & 63;
  int quad = lane >> 4, l16 = lane & 15;
  int brow = blockIdx.y * 64, bcol = blockIdx.x * 64;
  int m = brow + wv * 16 + l16;
  int ksteps = K >> 5;
  f4v acc[4] = {};
  const s8v* Arow = (const s8v*)(A + (size_t)m * K);
  for (int ks = 0; ks < ksteps; ks++) {
    s8v a = Arow[ks * 4 + quad];
#pragma unroll
    for (int nt = 0; nt < 4; nt++) {
      s8v b = Bp[(size_t)(((bcol >> 4) + nt) * ksteps + ks) * 64 + lane];
      acc[nt] = __builtin_amdgcn_mfma_f32_16x16x32_bf16(a, b, acc[nt], 0, 0, 0);
    }
  }
#pragma unroll
  for (int nt = 0; nt < 4; nt++) {
    float bv = bias ? bias[bcol + nt * 16 + l16] : 0.f;
#pragma unroll
    for (int r = 0; r < 4; r++)
      lds[(wv * 16 + quad * 4 + r) * 64 + nt * 16 + l16] = f2bf_bits(acc[nt][r] + bv);
  }
  __syncthreads();
#pragma unroll
  for (int rep = 0; rep < 2; rep++) {
    int idx = rep * 256 + tid;
    int row = idx >> 3, c16 = idx & 7;
    uint4 val = ((const uint4*)lds)[idx];
    *(uint4*)(C + (size_t)(brow + row) * ldc + bcol + c16 * 8) = val;
  }
}

// ---------------- merged ve/te GEMM ----------------
__global__ __launch_bounds__(256) void gemm_mfma_vt(const short* __restrict__ Av,
                                                    const s8v* __restrict__ Bpv,
                                                    const float* __restrict__ biasv,
                                                    const short* __restrict__ At,
                                                    const s8v* __restrict__ Bpt,
                                                    const float* __restrict__ biast,
                                                    short* __restrict__ C) {
  __shared__ short lds[64 * 64];
  bool isT = blockIdx.y >= 8;
  const short* A = isT ? At : Av;
  const s8v* Bp = isT ? Bpt : Bpv;
  const float* bias = isT ? biast : biasv;
  int coff = isT ? 128 : 0;
  int browIdx = isT ? (blockIdx.y - 8) : blockIdx.y;
  int tid = threadIdx.x;
  int wv = tid >> 6, lane = tid & 63;
  int quad = lane >> 4, l16 = lane & 15;
  int brow = browIdx * 64, bcol = blockIdx.x * 64;
  int m = brow + wv * 16 + l16;
  f4v acc[4] = {};
  const s8v* Arow = (const s8v*)(A + (size_t)m * 768);
  for (int ks = 0; ks < 24; ks++) {
    s8v a = Arow[ks * 4 + quad];
#pragma unroll
    for (int nt = 0; nt < 4; nt++) {
      s8v b = Bp[(size_t)(((bcol >> 4) + nt) * 24 + ks) * 64 + lane];
      acc[nt] = __builtin_amdgcn_mfma_f32_16x16x32_bf16(a, b, acc[nt], 0, 0, 0);
    }
  }
#pragma unroll
  for (int nt = 0; nt < 4; nt++) {
    float bv = bias[bcol + nt * 16 + l16];
#pragma unroll
    for (int r = 0; r < 4; r++)
      lds[(wv * 16 + quad * 4 + r) * 64 + nt * 16 + l16] = f2bf_bits(acc[nt][r] + bv);
  }
  __syncthreads();
#pragma unroll
  for (int rep = 0; rep < 2; rep++) {
    int idx = rep * 256 + tid;
    int row = idx >> 3, c16 = idx & 7;
    uint4 val = ((const uint4*)lds)[idx];
    *(uint4*)(C + (size_t)(brow + row) * 256 + coff + bcol + c16 * 8) = val;
  }
}

// ---------------- FUSED agg1 + conv1 head-GEMM + ELU + conv2 GEMM + al2 ----------------
__global__ __launch_bounds__(256) void agg_conv12_kernel(const uint4* __restrict__ x0,
                                                         const float4* __restrict__ aw4,
                                                         const float4* __restrict__ selfw4,
                                                         const float4* __restrict__ inv4,
                                                         const int* __restrict__ off,
                                                         const int* __restrict__ esrc,
                                                         const s8v* __restrict__ Bp1,
                                                         const float* __restrict__ b1,
                                                         const s8v* __restrict__ Bp2,
                                                         const float* __restrict__ a_src2,
                                                         const float* __restrict__ a_dst2,
                                                         short* __restrict__ xp2,
                                                         float* __restrict__ als2,
                                                         float* __restrict__ ald2) {
  __shared__ short lds[64 * LDW];
  int tid = threadIdx.x;
  int brow = blockIdx.y * 64;
  // ---- phase 0: aggregate y1 tile (64 nodes x 4 heads x 128) into LDS ----
  for (int it = 0; it < 4; it++) {
    int item = it * 256 + tid;        // 1024 items: (local node, c8)
    int ln = item >> 4, c8 = item & 15;
    int i = brow + ln;
    float4 sw = selfw4[i];
    uint4 xv = x0[(size_t)i * 16 + c8];
    float x[8];
    { float2 p0 = unpk(xv.x), p1 = unpk(xv.y), p2 = unpk(xv.z), p3 = unpk(xv.w);
      x[0]=p0.x; x[1]=p0.y; x[2]=p1.x; x[3]=p1.y; x[4]=p2.x; x[5]=p2.y; x[6]=p3.x; x[7]=p3.y; }
    float acc[4][8];
#pragma unroll
    for (int j = 0; j < 8; j++) {
      acc[0][j] = sw.x * x[j]; acc[1][j] = sw.y * x[j];
      acc[2][j] = sw.z * x[j]; acc[3][j] = sw.w * x[j];
    }
    int s0 = off[i], s1 = off[i + 1];
    for (int e = s0; e < s1; e++) {
      int s = esrc[e];
      float4 wv = aw4[e];
      uint4 m = x0[(size_t)s * 16 + c8];
      float2 q0 = unpk(m.x), q1 = unpk(m.y), q2 = unpk(m.z), q3 = unpk(m.w);
      float q[8] = {q0.x, q0.y, q1.x, q1.y, q2.x, q2.y, q3.x, q3.y};
#pragma unroll
      for (int j = 0; j < 8; j++) {
        acc[0][j] = fmaf(wv.x, q[j], acc[0][j]);
        acc[1][j] = fmaf(wv.y, q[j], acc[1][j]);
        acc[2][j] = fmaf(wv.z, q[j], acc[2][j]);
        acc[3][j] = fmaf(wv.w, q[j], acc[3][j]);
      }
    }
    float4 iv = inv4[i];
    float ivh[4] = {iv.x, iv.y, iv.z, iv.w};
#pragma unroll
    for (int h = 0; h < 4; h++) {
      uint4 o;
      o.x = pk(acc[h][0] * ivh[h], acc[h][1] * ivh[h]);
      o.y = pk(acc[h][2] * ivh[h], acc[h][3] * ivh[h]);
      o.z = pk(acc[h][4] * ivh[h], acc[h][5] * ivh[h]);
      o.w = pk(acc[h][6] * ivh[h], acc[h][7] * ivh[h]);
      *(uint4*)(lds + ln * LDW + h * 128 + c8 * 8) = o;
    }
  }
  __syncthreads();
  // ---- phase 1: in-place per-head GEMM + bias + ELU (wave touches only its own 16 rows) ----
  int wv = tid >> 6, lane = tid & 63;
  int quad = lane >> 4, l16 = lane & 15;
  for (int h = 0; h < 4; h++) {
    int arow = (wv * 16 + l16) * LDW + h * 128;
    // A-fragment layout: A[m=l16][k=quad*8+j] => element offset ks*32 + quad*8  (FIX r19: quad*8 term)
    s8v a0 = *(const s8v*)(lds + arow + 0 * 32 + quad * 8);
    s8v a1 = *(const s8v*)(lds + arow + 1 * 32 + quad * 8);
    s8v a2 = *(const s8v*)(lds + arow + 2 * 32 + quad * 8);
    s8v a3 = *(const s8v*)(lds + arow + 3 * 32 + quad * 8);
    f4v acc[8] = {};
#pragma unroll
    for (int nt = 0; nt < 8; nt++) {
      acc[nt] = __builtin_amdgcn_mfma_f32_16x16x32_bf16(a0, Bp1[(size_t)((h * 8 + nt) * 4 + 0) * 64 + lane], acc[nt], 0, 0, 0);
      acc[nt] = __builtin_amdgcn_mfma_f32_16x16x32_bf16(a1, Bp1[(size_t)((h * 8 + nt) * 4 + 1) * 64 + lane], acc[nt], 0, 0, 0);
      acc[nt] = __builtin_amdgcn_mfma_f32_16x16x32_bf16(a2, Bp1[(size_t)((h * 8 + nt) * 4 + 2) * 64 + lane], acc[nt], 0, 0, 0);
      acc[nt] = __builtin_amdgcn_mfma_f32_16x16x32_bf16(a3, Bp1[(size_t)((h * 8 + nt) * 4 + 3) * 64 + lane], acc[nt], 0, 0, 0);
    }
#pragma unroll
    for (int nt = 0; nt < 8; nt++) {
      float bv = b1[h * 128 + nt * 16 + l16];
#pragma unroll
      for (int r = 0; r < 4; r++) {
        float vv = acc[nt][r] + bv;
        vv = vv > 0.f ? vv : (__expf(vv) - 1.f);
        lds[(wv * 16 + quad * 4 + r) * LDW + h * 128 + nt * 16 + l16] = f2bf_bits(vv);
      }
    }
  }
  // ---- phase 2: xp2 = x1 @ W2 (K=512, N=128), A from own wave's rows ----
  f4v acc2[8] = {};
  int arow2 = (wv * 16 + l16) * LDW;
  for (int ks = 0; ks < 16; ks++) {
    s8v a = *(const s8v*)(lds + arow2 + ks * 32 + quad * 8);
#pragma unroll
    for (int nt = 0; nt < 8; nt++) {
      s8v b = Bp2[(size_t)(nt * 16 + ks) * 64 + lane];
      acc2[nt] = __builtin_amdgcn_mfma_f32_16x16x32_bf16(a, b, acc2[nt], 0, 0, 0);
    }
  }
#pragma unroll
  for (int nt = 0; nt < 8; nt++)
#pragma unroll
    for (int r = 0; r < 4; r++)
      lds[(wv * 16 + quad * 4 + r) * LDW + nt * 16 + l16] = f2bf_bits(acc2[nt][r]);
  // ---- phase 3: al2 scores for this wave's rows ----
  float2 as = ((const float2*)a_src2)[lane];
  float2 ad = ((const float2*)a_dst2)[lane];
  for (int r = 0; r < 16; r++) {
    int row = wv * 16 + r;
    float2 x = unpk(*(const unsigned*)(lds + row * LDW + lane * 2));
    float ps = wred_sum(x.x * as.x + x.y * as.y);
    float pd = wred_sum(x.x * ad.x + x.y * ad.y);
    if (lane == 0) { als2[brow + row] = ps; ald2[brow + row] = pd; }
  }
  __syncthreads();
  // ---- coalesced store of xp2 tile ----
#pragma unroll
  for (int rep = 0; rep < 4; rep++) {
    int idx = rep * 256 + tid;
    int row = idx >> 4, c16 = idx & 15;
    uint4 val = *(const uint4*)(lds + row * LDW + c16 * 8);
    *(uint4*)(xp2 + (size_t)(brow + row) * 128 + c16 * 8) = val;
  }
}

// ---------------- fused layernorm + conv1 scores (wave per node) ----------------
__global__ __launch_bounds__(256) void ln_al1_wave(const unsigned* __restrict__ start_b,
                                                   const unsigned* __restrict__ emb2_b,
                                                   const int* __restrict__ m_idx,
                                                   const float* __restrict__ lng,
                                                   const float* __restrict__ lnb,
                                                   const float* __restrict__ ws1,
                                                   const float* __restrict__ wd1,
                                                   unsigned* __restrict__ x0b,
                                                   float* __restrict__ als,
                                                   float* __restrict__ ald) {
  int i = blockIdx.x * 4 + (threadIdx.x >> 6);
  int lane = threadIdx.x & 63;
  int g = i >> 6, n = i & 63;
  const unsigned* row = (n == 0) ? (start_b + (size_t)g * 64) : (emb2_b + (size_t)m_idx[i] * 64);
  float2 v = unpk(row[lane]);
  float mu = wred_sum(v.x + v.y) * (1.f / 128.f);
  float dx = v.x - mu, dy = v.y - mu;
  float var = wred_sum(dx * dx + dy * dy) * (1.f / 128.f);
  float rstd = rsqrtf(var + 1e-6f);
  float2 gg = ((const float2*)lng)[lane];
  float2 bb = ((const float2*)lnb)[lane];
  float xx = dx * rstd * gg.x + bb.x;
  float xy = dy * rstd * gg.y + bb.y;
  x0b[(size_t)i * 64 + lane] = pk(xx, xy);
#pragma unroll
  for (int h = 0; h < 4; h++) {
    float2 s2 = ((const float2*)(ws1 + h * 128))[lane];
    float2 d2 = ((const float2*)(wd1 + h * 128))[lane];
    float ps = wred_sum(xx * s2.x + xy * s2.y);
    float pd = wred_sum(xx * d2.x + xy * d2.y);
    if (lane == 0) { als[i * 4 + h] = ps; ald[i * 4 + h] = pd; }
  }
}

// ---------------- softmax weights, single pass ----------------
__global__ __launch_bounds__(256) void alpha1_kernel(const float* __restrict__ als,
                                                     const float* __restrict__ ald,
                                                     const int* __restrict__ off,
                                                     const int* __restrict__ esrc,
                                                     float* __restrict__ aw,
                                                     float* __restrict__ selfw,
                                                     float* __restrict__ inv) {
  int id = blockIdx.x * 256 + threadIdx.x;
  if (id >= NN * 4) return;
  int i = id >> 2, h = id & 3;
  float adi = ald[id];
  float selfSc = als[id] + adi;
  selfSc = selfSc > 0.f ? selfSc : 0.2f * selfSc;
  float sw = __expf(selfSc);
  float denom = sw;
  int s0 = off[i], s1 = off[i + 1];
  for (int e = s0; e < s1; e++) {
    float sc = als[esrc[e] * 4 + h] + adi;
    sc = sc > 0.f ? sc : 0.2f * sc;
    float w = __expf(sc);
    aw[e * 4 + h] = w;
    denom += w;
  }
  selfw[id] = sw;
  inv[id] = 1.f / denom;
}

__global__ __launch_bounds__(256) void alpha2_kernel(const float* __restrict__ als,
                                                     const float* __restrict__ ald,
                                                     const int* __restrict__ off,
                                                     const int* __restrict__ esrc,
                                                     float* __restrict__ aw,
                                                     float* __restrict__ selfw,
                                                     float* __restrict__ inv) {
  int i = blockIdx.x * 256 + threadIdx.x;
  if (i >= NN) return;
  float adi = ald[i];
  float selfSc = als[i] + adi;
  selfSc = selfSc > 0.f ? selfSc : 0.2f * selfSc;
  float sw = __expf(selfSc);
  float denom = sw;
  int s0 = off[i], s1 = off[i + 1];
  for (int e = s0; e < s1; e++) {
    float sc = als[esrc[e]] + adi;
    sc = sc > 0.f ? sc : 0.2f * sc;
    float w = __expf(sc);
    aw[e] = w;
    denom += w;
  }
  selfw[i] = sw;
  inv[i] = 1.f / denom;
}

// ---------------- weighted gather, conv2: thread per (node, uint4); bf16 out ----------------
__global__ __launch_bounds__(256) void agg2w_kernel(const uint4* __restrict__ xp,
                                                    const float* __restrict__ aw,
                                                    const float* __restrict__ selfw,
                                                    const float* __restrict__ inv,
                                                    const int* __restrict__ off,
                                                    const int* __restrict__ esrc,
                                                    const float* __restrict__ b2,
                                                    uint4* __restrict__ x2b) {
  long gid = (long)blockIdx.x * 256 + threadIdx.x;
  if (gid >= (long)NN * 16) return;
  int i = (int)(gid >> 4), c8 = (int)(gid & 15);
  float sw = selfw[i];
  float iv = inv[i];
  uint4 xv = xp[(size_t)i * 16 + c8];
  float2 p0 = unpk(xv.x), p1 = unpk(xv.y), p2 = unpk(xv.z), p3 = unpk(xv.w);
  float a0 = sw * p0.x, a1 = sw * p0.y, a2 = sw * p1.x, a3 = sw * p1.y;
  float a4 = sw * p2.x, a5 = sw * p2.y, a6 = sw * p3.x, a7 = sw * p3.y;
  int s0 = off[i], s1 = off[i + 1];
  int e = s0;
  for (; e + 1 < s1; e += 2) {
    int sA = esrc[e], sB = esrc[e + 1];
    float wA = aw[e], wB = aw[e + 1];
    uint4 mA = xp[(size_t)sA * 16 + c8];
    uint4 mB = xp[(size_t)sB * 16 + c8];
    float2 q0 = unpk(mA.x), q1 = unpk(mA.y), q2 = unpk(mA.z), q3 = unpk(mA.w);
    a0 = fmaf(wA, q0.x, a0); a1 = fmaf(wA, q0.y, a1);
    a2 = fmaf(wA, q1.x, a2); a3 = fmaf(wA, q1.y, a3);
    a4 = fmaf(wA, q2.x, a4); a5 = fmaf(wA, q2.y, a5);
    a6 = fmaf(wA, q3.x, a6); a7 = fmaf(wA, q3.y, a7);
    q0 = unpk(mB.x); q1 = unpk(mB.y); q2 = unpk(mB.z); q3 = unpk(mB.w);
    a0 = fmaf(wB, q0.x, a0); a1 = fmaf(wB, q0.y, a1);
    a2 = fmaf(wB, q1.x, a2); a3 = fmaf(wB, q1.y, a3);
    a4 = fmaf(wB, q2.x, a4); a5 = fmaf(wB, q2.y, a5);
    a6 = fmaf(wB, q3.x, a6); a7 = fmaf(wB, q3.y, a7);
  }
  if (e < s1) {
    int sA = esrc[e];
    float wA = aw[e];
    uint4 mA = xp[(size_t)sA * 16 + c8];
    float2 q0 = unpk(mA.x), q1 = unpk(mA.y), q2 = unpk(mA.z), q3 = unpk(mA.w);
    a0 = fmaf(wA, q0.x, a0); a1 = fmaf(wA, q0.y, a1);
    a2 = fmaf(wA, q1.x, a2); a3 = fmaf(wA, q1.y, a3);
    a4 = fmaf(wA, q2.x, a4); a5 = fmaf(wA, q2.y, a5);
    a6 = fmaf(wA, q3.x, a6); a7 = fmaf(wA, q3.y, a7);
  }
  float4 bb0 = ((const float4*)b2)[c8 * 2];
  float4 bb1 = ((const float4*)b2)[c8 * 2 + 1];
  a0 = a0 * iv + bb0.x; a1 = a1 * iv + bb0.y; a2 = a2 * iv + bb0.z; a3 = a3 * iv + bb0.w;
  a4 = a4 * iv + bb1.x; a5 = a5 * iv + bb1.y; a6 = a6 * iv + bb1.z; a7 = a7 * iv + bb1.w;
  a0 = a0 > 0.f ? a0 : (__expf(a0) - 1.f);
  a1 = a1 > 0.f ? a1 : (__expf(a1) - 1.f);
  a2 = a2 > 0.f ? a2 : (__expf(a2) - 1.f);
  a3 = a3 > 0.f ? a3 : (__expf(a3) - 1.f);
  a4 = a4 > 0.f ? a4 : (__expf(a4) - 1.f);
  a5 = a5 > 0.f ? a5 : (__expf(a5) - 1.f);
  a6 = a6 > 0.f ? a6 : (__expf(a6) - 1.f);
  a7 = a7 > 0.f ? a7 : (__expf(a7) - 1.f);
  uint4 o;
  o.x = pk(a0, a1); o.y = pk(a2, a3); o.z = pk(a4, a5); o.w = pk(a6, a7);
  x2b[gid] = o;
}

// ---------------- fused pool + h1 GEMM + head2 (x2 bf16) ----------------
__global__ __launch_bounds__(128) void tail_kernel(const unsigned short* __restrict__ x2b,
                                                   const int* __restrict__ m_idx,
                                                   const float* __restrict__ Wo1,
                                                   const float* __restrict__ bo1,
                                                   const float* __restrict__ Wo2,
                                                   const float* __restrict__ bo2,
                                                   float* __restrict__ out) {
  __shared__ float pl[128];
  __shared__ float red[128];
  int g = blockIdx.x, c = threadIdx.x;
  float acc = 0.f, cnt = 0.f;
  const unsigned short* xr = x2b + (size_t)g * 64 * 128;
  const int* mi = m_idx + g * 64;
  for (int n = 0; n < 64; n++) {
    if (mi[n] >= 1) {
      cnt += 1.f;
      acc += __uint_as_float(((unsigned)xr[n * 128 + c]) << 16);
    }
  }
  pl[c] = acc / cnt;
  __syncthreads();
  float h = bo1[c];
  for (int k = 0; k < 128; k++) h = fmaf(pl[k], Wo1[(size_t)k * 128 + c], h);
  h = h > 0.f ? h : 0.01f * h;
  red[c] = h * Wo2[c];
  __syncthreads();
  for (int d = 64; d; d >>= 1) {
    if (c < d) red[c] += red[c + d];
    __syncthreads();
  }
  if (c == 0) out[g] = red[0] + bo2[0];
}

extern "C" void kernel_launch(void* const* d_in, const int* in_sizes, int n_in, void* d_out,
                              int out_size, void* d_ws, size_t ws_size, hipStream_t stream) {
  (void)n_in; (void)out_size; (void)ws_size;
  bool dict_order = (in_sizes[2] == NN);
  int IM, IE, IF[25];
  if (dict_order) {
    IM = 2; IE = 3;
    const int f[25] = {0, 1, 4, 5, 6, 7, 8, 9, 10, 11, 12, 13, 14, 15, 16, 17, 18,
                       19, 20, 21, 22, 23, 24, 25, 26};
    for (int k = 0; k < 25; k++) IF[k] = f[k];
  } else {
    IM = 25; IE = 26;
    for (int k = 0; k < 25; k++) IF[k] = k;
  }
  const int* m_idx = (const int*)d_in[IM];
  const int* eidx = (const int*)d_in[IE];
  float* out = (float*)d_out;
  const int* e_src = eidx;
  const int* e_dst = eidx + EE;

  const float* t = (const float*)d_in[IF[0]];
  const float* v = (const float*)d_in[IF[1]];
  const float* Wt = (const float*)d_in[IF[2]];     const float* bt = (const float*)d_in[IF[3]];
  const float* Wv = (const float*)d_in[IF[4]];     const float* bv = (const float*)d_in[IF[5]];
  const float* emb = (const float*)d_in[IF[6]];
  const float* Wnode = (const float*)d_in[IF[7]];  const float* bnode = (const float*)d_in[IF[8]];
  const float* Wstart = (const float*)d_in[IF[9]]; const float* bstart = (const float*)d_in[IF[10]];
  const float* ln_g = (const float*)d_in[IF[11]];  const float* ln_b = (const float*)d_in[IF[12]];
  const float* W1 = (const float*)d_in[IF[13]];
  const float* a_src1 = (const float*)d_in[IF[14]]; const float* a_dst1 = (const float*)d_in[IF[15]];
  const float* b1 = (const float*)d_in[IF[16]];
  const float* W2 = (const float*)d_in[IF[17]];
  const float* a_src2 = (const float*)d_in[IF[18]]; const float* a_dst2 = (const float*)d_in[IF[19]];
  const float* b2 = (const float*)d_in[IF[20]];
  const float* Wo1 = (const float*)d_in[IF[21]];   const float* bo1 = (const float*)d_in[IF[22]];
  const float* Wo2 = (const float*)d_in[IF[23]];   const float* bo2 = (const float*)d_in[IF[24]];

  // workspace layout (peak ~70 MB)
  char* w = (char*)d_ws;
  bf16* x0b = (bf16*)(w);                            // [NN,128] bf16 [0,8) MB
  bf16* xp2b = (bf16*)(w + ((size_t)8 << 20));       // [NN,128] bf16 [8,16) MB
  bf16* x2b = (bf16*)(w + ((size_t)16 << 20));       // [NN,128] bf16 [16,24) MB
  size_t so = (size_t)24 << 20;
  bf16* t_b = (bf16*)(w + so); so += 512 * 768 * 2;
  bf16* v_b = (bf16*)(w + so); so += 512 * 768 * 2;
  bf16* vt_b = (bf16*)(w + so); so += 512 * 256 * 2;
  bf16* start_b = (bf16*)(w + so); so += 512 * 128 * 2;
  bf16* emb2_b = (bf16*)(w + so); so += 51 * 128 * 2 + 256;
  float* als1 = (float*)(w + so); so += NN * 4 * 4;
  float* ald1 = (float*)(w + so); so += NN * 4 * 4;
  float* als2 = (float*)(w + so); so += NN * 4;
  float* ald2 = (float*)(w + so); so += NN * 4;
  float* aw1 = (float*)(w + so); so += EE * 4 * 4;   // 4 MB
  float* selfw1 = (float*)(w + so); so += NN * 4 * 4;
  float* inv1 = (float*)(w + so); so += NN * 4 * 4;
  float* aw2 = (float*)(w + so); so += EE * 4;       // 1 MB
  float* selfw2 = (float*)(w + so); so += NN * 4;
  float* inv2 = (float*)(w + so); so += NN * 4;
  float* ws1 = (float*)(w + so); so += 512 * 4;
  float* wd1 = (float*)(w + so); so += 512 * 4;
  int* indeg = (int*)(w + so); so += NN * 4;
  int* csroff = (int*)(w + so); so += (NN + 1) * 4 + 252;
  int* cursor = (int*)(w + so); so += NN * 4;
  int* esrc = (int*)(w + so); so += EE * 4;
  s8v* Bp1 = (s8v*)(w + so); so += 32 * 4 * 64 * 16;
  s8v* Bp2 = (s8v*)(w + so); so += 8 * 16 * 64 * 16;
  s8v* BpWv = (s8v*)(w + so); so += 8 * 24 * 64 * 16;
  s8v* BpWt = (s8v*)(w + so); so += 8 * 24 * 64 * 16;
  s8v* BpWs = (s8v*)(w + so); so += 8 * 8 * 64 * 16;

  // ---- CSR build ----
  hipMemsetAsync(indeg, 0, NN * 4, stream);
  hist_kernel<<<EE / 256, 256, 0, stream>>>(e_dst, indeg);
  scan_kernel<<<1, 1024, 0, stream>>>(indeg, csroff, cursor);
  fill_kernel<<<EE / 256, 256, 0, stream>>>(e_src, e_dst, cursor, esrc);

  // pack weights + convert t,v + fold conv1 score vectors
  packall_kernel<<<176, 256, 0, stream>>>(W1, Bp1, W2, Bp2, Wv, BpWv, Wt, BpWt, Wstart, BpWs);
  cvtpk2_kernel<<<1536, 256, 0, stream>>>((const float2*)t, (unsigned*)t_b,
                                          (const float2*)v, (unsigned*)v_b, 512 * 384);
  fold1_kernel<<<2, 256, 0, stream>>>(W1, a_src1, a_dst1, ws1, wd1);

  // emb2 (tiny), bf16 out
  sgemm_kernel<bf16><<<(51 * 128 + 63) / 64, 256, 0, stream>>>(emb, Wnode, bnode, emb2_b, 51, 128, 128, 128, 0);

  // ve+te merged, then start, via MFMA
  gemm_mfma_vt<<<dim3(2, 16), 256, 0, stream>>>((const short*)v_b, BpWv, bv,
                                                (const short*)t_b, BpWt, bt, (short*)vt_b);
  gemm_mfma<<<dim3(2, 8), 256, 0, stream>>>((const short*)vt_b, BpWs, bstart, (short*)start_b, 512, 128, 256, 128);

  // fused LN + conv1 scores
  ln_al1_wave<<<NN / 4, 256, 0, stream>>>((const unsigned*)start_b, (const unsigned*)emb2_b,
                                          m_idx, ln_g, ln_b, ws1, wd1, (unsigned*)x0b, als1, ald1);
  alpha1_kernel<<<NN * 4 / 256, 256, 0, stream>>>(als1, ald1, csroff, esrc, aw1, selfw1, inv1);

  // FUSED agg1 + conv1 head-GEMM + ELU + conv2 GEMM + al2
  agg_conv12_kernel<<<dim3(1, NN / 64), 256, 0, stream>>>(
      (const uint4*)x0b, (const float4*)aw1, (const float4*)selfw1, (const float4*)inv1,
      csroff, esrc, Bp1, b1, Bp2, a_src2, a_dst2, (short*)xp2b, als2, ald2);

  alpha2_kernel<<<NN / 256, 256, 0, stream>>>(als2, ald2, csroff, esrc, aw2, selfw2, inv2);
  agg2w_kernel<<<(int)(((long)NN * 16 + 255) / 256), 256, 0, stream>>>(
      (const uint4*)xp2b, aw2, selfw2, inv2, csroff, esrc, b2, (uint4*)x2b);

  // fused pool + h1 + head (x2 bf16)
  tail_kernel<<<GG, 128, 0, stream>>>((const unsigned short*)x2b, m_idx, Wo1, bo1, Wo2, bo2, out);
}

// Round 21
// 335.047 us; speedup vs baseline: 1.0295x; 1.0295x over previous
//
#include <hip/hip_runtime.h>
#include <hip/hip_bf16.h>

typedef __hip_bfloat16 bf16;
typedef __attribute__((ext_vector_type(8))) short s8v;   // 8 bf16 (4 VGPRs)
typedef __attribute__((ext_vector_type(4))) float f4v;   // 4 fp32 acc

#define NN 32768   // total nodes
#define EE 262144  // edges
#define GG 512     // graphs
#define LDW 520    // padded LDS row stride (bf16 elems)

__device__ __forceinline__ float2 unpk(unsigned u) {
  float2 r;
  r.x = __uint_as_float(u << 16);
  r.y = __uint_as_float(u & 0xffff0000u);
  return r;
}
__device__ __forceinline__ unsigned pk(float x, float y) {
  union { bf16 h[2]; unsigned u; } p;
  p.h[0] = __float2bfloat16(x);
  p.h[1] = __float2bfloat16(y);
  return p.u;
}
__device__ __forceinline__ short f2bf_bits(float x) {
  bf16 h = __float2bfloat16(x);
  return *reinterpret_cast<short*>(&h);
}
__device__ __forceinline__ void storef(float* p, float v) { *p = v; }
__device__ __forceinline__ void storef(bf16* p, float v) { *p = __float2bfloat16(v); }

__device__ __forceinline__ float wred_sum(float v) {
#pragma unroll
  for (int o = 32; o; o >>= 1) v += __shfl_xor(v, o, 64);
  return v;
}

// ---------------- CSR build ----------------
__global__ __launch_bounds__(256) void hist_kernel(const int* __restrict__ dst,
                                                   int* __restrict__ indeg) {
  int e = blockIdx.x * 256 + threadIdx.x;
  if (e < EE) atomicAdd(&indeg[dst[e]], 1);
}

__global__ __launch_bounds__(1024) void scan_kernel(const int* __restrict__ indeg,
                                                    int* __restrict__ off,
                                                    int* __restrict__ cursor) {
  __shared__ int sh[1024];
  int t = threadIdx.x;
  int loc[32];
  int s = 0;
  int base = t * 32;
#pragma unroll
  for (int j = 0; j < 32; j++) { loc[j] = indeg[base + j]; s += loc[j]; }
  sh[t] = s;
  __syncthreads();
  for (int d = 1; d < 1024; d <<= 1) {
    int v = (t >= d) ? sh[t - d] : 0;
    __syncthreads();
    sh[t] += v;
    __syncthreads();
  }
  int run = (t == 0) ? 0 : sh[t - 1];
#pragma unroll
  for (int j = 0; j < 32; j++) { off[base + j] = run; cursor[base + j] = run; run += loc[j]; }
  if (t == 1023) off[NN] = run;
}

__global__ __launch_bounds__(256) void fill_kernel(const int* __restrict__ src,
                                                   const int* __restrict__ dst,
                                                   int* __restrict__ cursor,
                                                   int* __restrict__ esrc) {
  int e = blockIdx.x * 256 + threadIdx.x;
  if (e < EE) {
    int p = atomicAdd(&cursor[dst[e]], 1);
    esrc[p] = src[e];
  }
}

// ---------------- fp32 -> packed bf16 conversion (t and v in one launch) ----------------
__global__ __launch_bounds__(256) void cvtpk2_kernel(const float2* __restrict__ a,
                                                     unsigned* __restrict__ da,
                                                     const float2* __restrict__ b,
                                                     unsigned* __restrict__ db, int n2) {
  int id = blockIdx.x * 256 + threadIdx.x;
  if (id < n2) { float2 v = a[id]; da[id] = pk(v.x, v.y); }
  else if (id < 2 * n2) { int j = id - n2; float2 v = b[j]; db[j] = pk(v.x, v.y); }
}

// ---------------- small GEMM, split-K (tiny problems) ----------------
template <typename TC>
__global__ __launch_bounds__(256) void sgemm_kernel(const float* __restrict__ A,
                                                    const float* __restrict__ B,
                                                    const float* __restrict__ bias,
                                                    TC* __restrict__ C,
                                                    int M, int N, int K, int ldc, int act) {
  __shared__ float red[256];
  int tid = threadIdx.x;
  int lo = tid & 63;
  int slice = tid >> 6;
  long oid = (long)blockIdx.x * 64 + lo;
  bool live = (oid < (long)M * N);
  int m = 0, n = 0;
  if (live) { m = (int)(oid / N); n = (int)(oid % N); }
  int kq = K >> 2;
  int k0 = slice * kq, k1 = k0 + kq;
  float acc = 0.f;
  if (live) {
    const float* Ar = A + (size_t)m * K;
    for (int k = k0; k < k1; k++) acc = fmaf(Ar[k], B[(size_t)k * N + n], acc);
  }
  red[tid] = acc;
  __syncthreads();
  if (slice == 0 && live) {
    float v = red[lo] + red[64 + lo] + red[128 + lo] + red[192 + lo];
    if (bias) v += bias[n];
    if (act == 1) v = v > 0.f ? v : 0.01f * v;
    storef(&C[(size_t)m * ldc + n], v);
  }
}

// ---------------- pack all 5 weights into MFMA B-fragment order, one launch ----------------
__device__ __forceinline__ void packB_one(const float* W, int N, int K, int id, s8v* Bp) {
  int lane = id & 63;
  int tmp = id >> 6;
  int ksteps = K >> 5;
  int ks = tmp % ksteps;
  int nt = tmp / ksteps;
  int n = nt * 16 + (lane & 15);
  int kbase = ks * 32 + (lane >> 4) * 8;
  s8v r;
#pragma unroll
  for (int j = 0; j < 8; j++) r[j] = f2bf_bits(W[(size_t)(kbase + j) * N + n]);
  Bp[id] = r;
}

__global__ __launch_bounds__(256) void packall_kernel(const float* __restrict__ W1, s8v* Bp1,
                                                      const float* __restrict__ W2, s8v* Bp2,
                                                      const float* __restrict__ Wv, s8v* BpWv,
                                                      const float* __restrict__ Wt, s8v* BpWt,
                                                      const float* __restrict__ Ws, s8v* BpWs) {
  int b = blockIdx.x;
  if (b < 32)        packB_one(W1, 512, 128, b * 256 + threadIdx.x, Bp1);
  else if (b < 64)   packB_one(W2, 128, 512, (b - 32) * 256 + threadIdx.x, Bp2);
  else if (b < 112)  packB_one(Wv, 128, 768, (b - 64) * 256 + threadIdx.x, BpWv);
  else if (b < 160)  packB_one(Wt, 128, 768, (b - 112) * 256 + threadIdx.x, BpWt);
  else               packB_one(Ws, 128, 256, (b - 160) * 256 + threadIdx.x, BpWs);
}

// ---------------- fold a_src/a_dst through W1 ----------------
__global__ __launch_bounds__(256) void fold1_kernel(const float* __restrict__ W1,
                                                    const float* __restrict__ a_src1,
                                                    const float* __restrict__ a_dst1,
                                                    float* __restrict__ ws1,
                                                    float* __restrict__ wd1) {
  int id = blockIdx.x * 256 + threadIdx.x;
  if (id >= 512) return;
  int h = id >> 7, k = id & 127;
  float s = 0.f, d = 0.f;
  for (int c = 0; c < 128; c++) {
    float w = W1[(size_t)k * 512 + h * 128 + c];
    s = fmaf(w, a_src1[h * 128 + c], s);
    d = fmaf(w, a_dst1[h * 128 + c], d);
  }
  ws1[id] = s;
  wd1[id] = d;
}

// ---------------- MFMA bf16 GEMM, optional fp32 bias, bf16 out with ldc ----------------
__global__ __launch_bounds__(256) void gemm_mfma(const short* __restrict__ A,
                                                 const s8v* __restrict__ Bp,
                                                 const float* __restrict__ bias,
                                                 short* __restrict__ C,
                                                 int M, int N, int K, int ldc) {
  __shared__ short lds[64 * 64];
  int tid = threadIdx.x;
  int wv = tid >> 6, lane = tid & 63;
  int quad = lane >> 4, l16 = lane & 15;
  int brow = blockIdx.y * 64, bcol = blockIdx.x * 64;
  int m = brow + wv * 16 + l16;
  int ksteps = K >> 5;
  f4v acc[4] = {};
  const s8v* Arow = (const s8v*)(A + (size_t)m * K);
  for (int ks = 0; ks < ksteps; ks++) {
    s8v a = Arow[ks * 4 + quad];
#pragma unroll
    for (int nt = 0; nt < 4; nt++) {
      s8v b = Bp[(size_t)(((bcol >> 4) + nt) * ksteps + ks) * 64 + lane];
      acc[nt] = __builtin_amdgcn_mfma_f32_16x16x32_bf16(a, b, acc[nt], 0, 0, 0);
    }
  }
#pragma unroll
  for (int nt = 0; nt < 4; nt++) {
    float bv = bias ? bias[bcol + nt * 16 + l16] : 0.f;
#pragma unroll
    for (int r = 0; r < 4; r++)
      lds[(wv * 16 + quad * 4 + r) * 64 + nt * 16 + l16] = f2bf_bits(acc[nt][r] + bv);
  }
  __syncthreads();
#pragma unroll
  for (int rep = 0; rep < 2; rep++) {
    int idx = rep * 256 + tid;
    int row = idx >> 3, c16 = idx & 7;
    uint4 val = ((const uint4*)lds)[idx];
    *(uint4*)(C + (size_t)(brow + row) * ldc + bcol + c16 * 8) = val;
  }
}

// ---------------- merged ve/te GEMM ----------------
__global__ __launch_bounds__(256) void gemm_mfma_vt(const short* __restrict__ Av,
                                                    const s8v* __restrict__ Bpv,
                                                    const float* __restrict__ biasv,
                                                    const short* __restrict__ At,
                                                    const s8v* __restrict__ Bpt,
                                                    const float* __restrict__ biast,
                                                    short* __restrict__ C) {
  __shared__ short lds[64 * 64];
  bool isT = blockIdx.y >= 8;
  const short* A = isT ? At : Av;
  const s8v* Bp = isT ? Bpt : Bpv;
  const float* bias = isT ? biast : biasv;
  int coff = isT ? 128 : 0;
  int browIdx = isT ? (blockIdx.y - 8) : blockIdx.y;
  int tid = threadIdx.x;
  int wv = tid >> 6, lane = tid & 63;
  int quad = lane >> 4, l16 = lane & 15;
  int brow = browIdx * 64, bcol = blockIdx.x * 64;
  int m = brow + wv * 16 + l16;
  f4v acc[4] = {};
  const s8v* Arow = (const s8v*)(A + (size_t)m * 768);
  for (int ks = 0; ks < 24; ks++) {
    s8v a = Arow[ks * 4 + quad];
#pragma unroll
    for (int nt = 0; nt < 4; nt++) {
      s8v b = Bp[(size_t)(((bcol >> 4) + nt) * 24 + ks) * 64 + lane];
      acc[nt] = __builtin_amdgcn_mfma_f32_16x16x32_bf16(a, b, acc[nt], 0, 0, 0);
    }
  }
#pragma unroll
  for (int nt = 0; nt < 4; nt++) {
    float bv = bias[bcol + nt * 16 + l16];
#pragma unroll
    for (int r = 0; r < 4; r++)
      lds[(wv * 16 + quad * 4 + r) * 64 + nt * 16 + l16] = f2bf_bits(acc[nt][r] + bv);
  }
  __syncthreads();
#pragma unroll
  for (int rep = 0; rep < 2; rep++) {
    int idx = rep * 256 + tid;
    int row = idx >> 3, c16 = idx & 7;
    uint4 val = ((const uint4*)lds)[idx];
    *(uint4*)(C + (size_t)(brow + row) * 256 + coff + bcol + c16 * 8) = val;
  }
}

// ---------------- conv1 aggregation in input space (high occupancy, separate kernel) ----------------
__global__ __launch_bounds__(256) void agg1y_kernel(const uint4* __restrict__ x0,
                                                    const float4* __restrict__ aw4,
                                                    const float4* __restrict__ selfw4,
                                                    const float4* __restrict__ inv4,
                                                    const int* __restrict__ off,
                                                    const int* __restrict__ esrc,
                                                    uint4* __restrict__ y1) {
  long gid = (long)blockIdx.x * 256 + threadIdx.x;
  if (gid >= (long)NN * 16) return;
  int i = (int)(gid >> 4), c8 = (int)(gid & 15);
  float4 sw = selfw4[i];
  uint4 xv = x0[(size_t)i * 16 + c8];
  float x[8];
  { float2 p0 = unpk(xv.x), p1 = unpk(xv.y), p2 = unpk(xv.z), p3 = unpk(xv.w);
    x[0]=p0.x; x[1]=p0.y; x[2]=p1.x; x[3]=p1.y; x[4]=p2.x; x[5]=p2.y; x[6]=p3.x; x[7]=p3.y; }
  float acc[4][8];
#pragma unroll
  for (int j = 0; j < 8; j++) {
    acc[0][j] = sw.x * x[j]; acc[1][j] = sw.y * x[j];
    acc[2][j] = sw.z * x[j]; acc[3][j] = sw.w * x[j];
  }
  int s0 = off[i], s1 = off[i + 1];
  for (int e = s0; e < s1; e++) {
    int s = esrc[e];
    float4 wv = aw4[e];
    uint4 m = x0[(size_t)s * 16 + c8];
    float2 q0 = unpk(m.x), q1 = unpk(m.y), q2 = unpk(m.z), q3 = unpk(m.w);
    float q[8] = {q0.x, q0.y, q1.x, q1.y, q2.x, q2.y, q3.x, q3.y};
#pragma unroll
    for (int j = 0; j < 8; j++) {
      acc[0][j] = fmaf(wv.x, q[j], acc[0][j]);
      acc[1][j] = fmaf(wv.y, q[j], acc[1][j]);
      acc[2][j] = fmaf(wv.z, q[j], acc[2][j]);
      acc[3][j] = fmaf(wv.w, q[j], acc[3][j]);
    }
  }
  float4 iv = inv4[i];
  float ivh[4] = {iv.x, iv.y, iv.z, iv.w};
#pragma unroll
  for (int h = 0; h < 4; h++) {
    uint4 o;
    o.x = pk(acc[h][0] * ivh[h], acc[h][1] * ivh[h]);
    o.y = pk(acc[h][2] * ivh[h], acc[h][3] * ivh[h]);
    o.z = pk(acc[h][4] * ivh[h], acc[h][5] * ivh[h]);
    o.w = pk(acc[h][6] * ivh[h], acc[h][7] * ivh[h]);
    y1[((size_t)i * 4 + h) * 16 + c8] = o;
  }
}

// ---------------- FUSED conv1 head-GEMM + ELU + conv2 GEMM + al2 scores (from global y1) ----------------
__global__ __launch_bounds__(256) void conv12_kernel(const short* __restrict__ y1,
                                                     const s8v* __restrict__ Bp1,
                                                     const float* __restrict__ b1,
                                                     const s8v* __restrict__ Bp2,
                                                     const float* __restrict__ a_src2,
                                                     const float* __restrict__ a_dst2,
                                                     short* __restrict__ xp2,
                                                     float* __restrict__ als2,
                                                     float* __restrict__ ald2) {
  __shared__ short lds[64 * LDW];
  int tid = threadIdx.x;
  int wv = tid >> 6, lane = tid & 63;
  int quad = lane >> 4, l16 = lane & 15;
  int brow = blockIdx.y * 64;
  int m = brow + wv * 16 + l16;
  // phase 1: x1 = ELU(y1 @ W1_head + b1) -> LDS
  for (int h = 0; h < 4; h++) {
    f4v acc[8] = {};
    const s8v* Arow = (const s8v*)(y1 + (size_t)m * 512 + h * 128);
#pragma unroll
    for (int ks = 0; ks < 4; ks++) {
      s8v a = Arow[ks * 4 + quad];
#pragma unroll
      for (int nt = 0; nt < 8; nt++) {
        s8v b = Bp1[(size_t)((h * 8 + nt) * 4 + ks) * 64 + lane];
        acc[nt] = __builtin_amdgcn_mfma_f32_16x16x32_bf16(a, b, acc[nt], 0, 0, 0);
      }
    }
#pragma unroll
    for (int nt = 0; nt < 8; nt++) {
      float bv = b1[h * 128 + nt * 16 + l16];
#pragma unroll
      for (int r = 0; r < 4; r++) {
        float vv = acc[nt][r] + bv;
        vv = vv > 0.f ? vv : (__expf(vv) - 1.f);
        lds[(wv * 16 + quad * 4 + r) * LDW + h * 128 + nt * 16 + l16] = f2bf_bits(vv);
      }
    }
  }
  __syncthreads();
  // phase 2: xp2 = x1 @ W2 (K=512, N=128), A from own wave's rows
  f4v acc2[8] = {};
  int arow = (wv * 16 + l16) * LDW;
  for (int ks = 0; ks < 16; ks++) {
    s8v a = *(const s8v*)(lds + arow + ks * 32 + quad * 8);
#pragma unroll
    for (int nt = 0; nt < 8; nt++) {
      s8v b = Bp2[(size_t)(nt * 16 + ks) * 64 + lane];
      acc2[nt] = __builtin_amdgcn_mfma_f32_16x16x32_bf16(a, b, acc2[nt], 0, 0, 0);
    }
  }
#pragma unroll
  for (int nt = 0; nt < 8; nt++)
#pragma unroll
    for (int r = 0; r < 4; r++)
      lds[(wv * 16 + quad * 4 + r) * LDW + nt * 16 + l16] = f2bf_bits(acc2[nt][r]);
  // phase 3: al2 scores for this wave's rows
  float2 as = ((const float2*)a_src2)[lane];
  float2 ad = ((const float2*)a_dst2)[lane];
  for (int r = 0; r < 16; r++) {
    int row = wv * 16 + r;
    float2 x = unpk(*(const unsigned*)(lds + row * LDW + lane * 2));
    float ps = wred_sum(x.x * as.x + x.y * as.y);
    float pd = wred_sum(x.x * ad.x + x.y * ad.y);
    if (lane == 0) { als2[brow + row] = ps; ald2[brow + row] = pd; }
  }
  __syncthreads();
  // coalesced store of xp2 tile
#pragma unroll
  for (int rep = 0; rep < 4; rep++) {
    int idx = rep * 256 + tid;
    int row = idx >> 4, c16 = idx & 15;
    uint4 val = *(const uint4*)(lds + row * LDW + c16 * 8);
    *(uint4*)(xp2 + (size_t)(brow + row) * 128 + c16 * 8) = val;
  }
}

// ---------------- fused layernorm + conv1 scores (wave per node) ----------------
__global__ __launch_bounds__(256) void ln_al1_wave(const unsigned* __restrict__ start_b,
                                                   const unsigned* __restrict__ emb2_b,
                                                   const int* __restrict__ m_idx,
                                                   const float* __restrict__ lng,
                                                   const float* __restrict__ lnb,
                                                   const float* __restrict__ ws1,
                                                   const float* __restrict__ wd1,
                                                   unsigned* __restrict__ x0b,
                                                   float* __restrict__ als,
                                                   float* __restrict__ ald) {
  int i = blockIdx.x * 4 + (threadIdx.x >> 6);
  int lane = threadIdx.x & 63;
  int g = i >> 6, n = i & 63;
  const unsigned* row = (n == 0) ? (start_b + (size_t)g * 64) : (emb2_b + (size_t)m_idx[i] * 64);
  float2 v = unpk(row[lane]);
  float mu = wred_sum(v.x + v.y) * (1.f / 128.f);
  float dx = v.x - mu, dy = v.y - mu;
  float var = wred_sum(dx * dx + dy * dy) * (1.f / 128.f);
  float rstd = rsqrtf(var + 1e-6f);
  float2 gg = ((const float2*)lng)[lane];
  float2 bb = ((const float2*)lnb)[lane];
  float xx = dx * rstd * gg.x + bb.x;
  float xy = dy * rstd * gg.y + bb.y;
  x0b[(size_t)i * 64 + lane] = pk(xx, xy);
#pragma unroll
  for (int h = 0; h < 4; h++) {
    float2 s2 = ((const float2*)(ws1 + h * 128))[lane];
    float2 d2 = ((const float2*)(wd1 + h * 128))[lane];
    float ps = wred_sum(xx * s2.x + xy * s2.y);
    float pd = wred_sum(xx * d2.x + xy * d2.y);
    if (lane == 0) { als[i * 4 + h] = ps; ald[i * 4 + h] = pd; }
  }
}

// ---------------- softmax weights, single pass ----------------
__global__ __launch_bounds__(256) void alpha1_kernel(const float* __restrict__ als,
                                                     const float* __restrict__ ald,
                                                     const int* __restrict__ off,
                                                     const int* __restrict__ esrc,
                                                     float* __restrict__ aw,
                                                     float* __restrict__ selfw,
                                                     float* __restrict__ inv) {
  int id = blockIdx.x * 256 + threadIdx.x;
  if (id >= NN * 4) return;
  int i = id >> 2, h = id & 3;
  float adi = ald[id];
  float selfSc = als[id] + adi;
  selfSc = selfSc > 0.f ? selfSc : 0.2f * selfSc;
  float sw = __expf(selfSc);
  float denom = sw;
  int s0 = off[i], s1 = off[i + 1];
  for (int e = s0; e < s1; e++) {
    float sc = als[esrc[e] * 4 + h] + adi;
    sc = sc > 0.f ? sc : 0.2f * sc;
    float w = __expf(sc);
    aw[e * 4 + h] = w;
    denom += w;
  }
  selfw[id] = sw;
  inv[id] = 1.f / denom;
}

__global__ __launch_bounds__(256) void alpha2_kernel(const float* __restrict__ als,
                                                     const float* __restrict__ ald,
                                                     const int* __restrict__ off,
                                                     const int* __restrict__ esrc,
                                                     float* __restrict__ aw,
                                                     float* __restrict__ selfw,
                                                     float* __restrict__ inv) {
  int i = blockIdx.x * 256 + threadIdx.x;
  if (i >= NN) return;
  float adi = ald[i];
  float selfSc = als[i] + adi;
  selfSc = selfSc > 0.f ? selfSc : 0.2f * selfSc;
  float sw = __expf(selfSc);
  float denom = sw;
  int s0 = off[i], s1 = off[i + 1];
  for (int e = s0; e < s1; e++) {
    float sc = als[esrc[e]] + adi;
    sc = sc > 0.f ? sc : 0.2f * sc;
    float w = __expf(sc);
    aw[e] = w;
    denom += w;
  }
  selfw[i] = sw;
  inv[i] = 1.f / denom;
}

// ---------------- weighted gather, conv2: thread per (node, uint4); bf16 out ----------------
__global__ __launch_bounds__(256) void agg2w_kernel(const uint4* __restrict__ xp,
                                                    const float* __restrict__ aw,
                                                    const float* __restrict__ selfw,
                                                    const float* __restrict__ inv,
                                                    const int* __restrict__ off,
                                                    const int* __restrict__ esrc,
                                                    const float* __restrict__ b2,
                                                    uint4* __restrict__ x2b) {
  long gid = (long)blockIdx.x * 256 + threadIdx.x;
  if (gid >= (long)NN * 16) return;
  int i = (int)(gid >> 4), c8 = (int)(gid & 15);
  float sw = selfw[i];
  float iv = inv[i];
  uint4 xv = xp[(size_t)i * 16 + c8];
  float2 p0 = unpk(xv.x), p1 = unpk(xv.y), p2 = unpk(xv.z), p3 = unpk(xv.w);
  float a0 = sw * p0.x, a1 = sw * p0.y, a2 = sw * p1.x, a3 = sw * p1.y;
  float a4 = sw * p2.x, a5 = sw * p2.y, a6 = sw * p3.x, a7 = sw * p3.y;
  int s0 = off[i], s1 = off[i + 1];
  int e = s0;
  for (; e + 1 < s1; e += 2) {
    int sA = esrc[e], sB = esrc[e + 1];
    float wA = aw[e], wB = aw[e + 1];
    uint4 mA = xp[(size_t)sA * 16 + c8];
    uint4 mB = xp[(size_t)sB * 16 + c8];
    float2 q0 = unpk(mA.x), q1 = unpk(mA.y), q2 = unpk(mA.z), q3 = unpk(mA.w);
    a0 = fmaf(wA, q0.x, a0); a1 = fmaf(wA, q0.y, a1);
    a2 = fmaf(wA, q1.x, a2); a3 = fmaf(wA, q1.y, a3);
    a4 = fmaf(wA, q2.x, a4); a5 = fmaf(wA, q2.y, a5);
    a6 = fmaf(wA, q3.x, a6); a7 = fmaf(wA, q3.y, a7);
    q0 = unpk(mB.x); q1 = unpk(mB.y); q2 = unpk(mB.z); q3 = unpk(mB.w);
    a0 = fmaf(wB, q0.x, a0); a1 = fmaf(wB, q0.y, a1);
    a2 = fmaf(wB, q1.x, a2); a3 = fmaf(wB, q1.y, a3);
    a4 = fmaf(wB, q2.x, a4); a5 = fmaf(wB, q2.y, a5);
    a6 = fmaf(wB, q3.x, a6); a7 = fmaf(wB, q3.y, a7);
  }
  if (e < s1) {
    int sA = esrc[e];
    float wA = aw[e];
    uint4 mA = xp[(size_t)sA * 16 + c8];
    float2 q0 = unpk(mA.x), q1 = unpk(mA.y), q2 = unpk(mA.z), q3 = unpk(mA.w);
    a0 = fmaf(wA, q0.x, a0); a1 = fmaf(wA, q0.y, a1);
    a2 = fmaf(wA, q1.x, a2); a3 = fmaf(wA, q1.y, a3);
    a4 = fmaf(wA, q2.x, a4); a5 = fmaf(wA, q2.y, a5);
    a6 = fmaf(wA, q3.x, a6); a7 = fmaf(wA, q3.y, a7);
  }
  float4 bb0 = ((const float4*)b2)[c8 * 2];
  float4 bb1 = ((const float4*)b2)[c8 * 2 + 1];
  a0 = a0 * iv + bb0.x; a1 = a1 * iv + bb0.y; a2 = a2 * iv + bb0.z; a3 = a3 * iv + bb0.w;
  a4 = a4 * iv + bb1.x; a5 = a5 * iv + bb1.y; a6 = a6 * iv + bb1.z; a7 = a7 * iv + bb1.w;
  a0 = a0 > 0.f ? a0 : (__expf(a0) - 1.f);
  a1 = a1 > 0.f ? a1 : (__expf(a1) - 1.f);
  a2 = a2 > 0.f ? a2 : (__expf(a2) - 1.f);
  a3 = a3 > 0.f ? a3 : (__expf(a3) - 1.f);
  a4 = a4 > 0.f ? a4 : (__expf(a4) - 1.f);
  a5 = a5 > 0.f ? a5 : (__expf(a5) - 1.f);
  a6 = a6 > 0.f ? a6 : (__expf(a6) - 1.f);
  a7 = a7 > 0.f ? a7 : (__expf(a7) - 1.f);
  uint4 o;
  o.x = pk(a0, a1); o.y = pk(a2, a3); o.z = pk(a4, a5); o.w = pk(a6, a7);
  x2b[gid] = o;
}

// ---------------- fused pool + h1 GEMM + head2 (x2 bf16) ----------------
__global__ __launch_bounds__(128) void tail_kernel(const unsigned short* __restrict__ x2b,
                                                   const int* __restrict__ m_idx,
                                                   const float* __restrict__ Wo1,
                                                   const float* __restrict__ bo1,
                                                   const float* __restrict__ Wo2,
                                                   const float* __restrict__ bo2,
                                                   float* __restrict__ out) {
  __shared__ float pl[128];
  __shared__ float red[128];
  int g = blockIdx.x, c = threadIdx.x;
  float acc = 0.f, cnt = 0.f;
  const unsigned short* xr = x2b + (size_t)g * 64 * 128;
  const int* mi = m_idx + g * 64;
  for (int n = 0; n < 64; n++) {
    if (mi[n] >= 1) {
      cnt += 1.f;
      acc += __uint_as_float(((unsigned)xr[n * 128 + c]) << 16);
    }
  }
  pl[c] = acc / cnt;
  __syncthreads();
  float h = bo1[c];
  for (int k = 0; k < 128; k++) h = fmaf(pl[k], Wo1[(size_t)k * 128 + c], h);
  h = h > 0.f ? h : 0.01f * h;
  red[c] = h * Wo2[c];
  __syncthreads();
  for (int d = 64; d; d >>= 1) {
    if (c < d) red[c] += red[c + d];
    __syncthreads();
  }
  if (c == 0) out[g] = red[0] + bo2[0];
}

extern "C" void kernel_launch(void* const* d_in, const int* in_sizes, int n_in, void* d_out,
                              int out_size, void* d_ws, size_t ws_size, hipStream_t stream) {
  (void)n_in; (void)out_size; (void)ws_size;
  bool dict_order = (in_sizes[2] == NN);
  int IM, IE, IF[25];
  if (dict_order) {
    IM = 2; IE = 3;
    const int f[25] = {0, 1, 4, 5, 6, 7, 8, 9, 10, 11, 12, 13, 14, 15, 16, 17, 18,
                       19, 20, 21, 22, 23, 24, 25, 26};
    for (int k = 0; k < 25; k++) IF[k] = f[k];
  } else {
    IM = 25; IE = 26;
    for (int k = 0; k < 25; k++) IF[k] = k;
  }
  const int* m_idx = (const int*)d_in[IM];
  const int* eidx = (const int*)d_in[IE];
  float* out = (float*)d_out;
  const int* e_src = eidx;
  const int* e_dst = eidx + EE;

  const float* t = (const float*)d_in[IF[0]];
  const float* v = (const float*)d_in[IF[1]];
  const float* Wt = (const float*)d_in[IF[2]];     const float* bt = (const float*)d_in[IF[3]];
  const float* Wv = (const float*)d_in[IF[4]];     const float* bv = (const float*)d_in[IF[5]];
  const float* emb = (const float*)d_in[IF[6]];
  const float* Wnode = (const float*)d_in[IF[7]];  const float* bnode = (const float*)d_in[IF[8]];
  const float* Wstart = (const float*)d_in[IF[9]]; const float* bstart = (const float*)d_in[IF[10]];
  const float* ln_g = (const float*)d_in[IF[11]];  const float* ln_b = (const float*)d_in[IF[12]];
  const float* W1 = (const float*)d_in[IF[13]];
  const float* a_src1 = (const float*)d_in[IF[14]]; const float* a_dst1 = (const float*)d_in[IF[15]];
  const float* b1 = (const float*)d_in[IF[16]];
  const float* W2 = (const float*)d_in[IF[17]];
  const float* a_src2 = (const float*)d_in[IF[18]]; const float* a_dst2 = (const float*)d_in[IF[19]];
  const float* b2 = (const float*)d_in[IF[20]];
  const float* Wo1 = (const float*)d_in[IF[21]];   const float* bo1 = (const float*)d_in[IF[22]];
  const float* Wo2 = (const float*)d_in[IF[23]];   const float* bo2 = (const float*)d_in[IF[24]];

  // workspace layout (peak ~72 MB)
  char* w = (char*)d_ws;
  bf16* y1 = (bf16*)(w);                             // [NN,512] bf16 [0,32) MB
  bf16* x0b = (bf16*)(w + ((size_t)32 << 20));       // [NN,128] bf16 [32,40) MB
  bf16* xp2b = (bf16*)(w + ((size_t)40 << 20));      // [NN,128] bf16 [40,48) MB
  bf16* x2b = (bf16*)(w + ((size_t)48 << 20));       // [NN,128] bf16 [48,56) MB
  size_t so = (size_t)56 << 20;
  bf16* t_b = (bf16*)(w + so); so += 512 * 768 * 2;
  bf16* v_b = (bf16*)(w + so); so += 512 * 768 * 2;
  bf16* vt_b = (bf16*)(w + so); so += 512 * 256 * 2;
  bf16* start_b = (bf16*)(w + so); so += 512 * 128 * 2;
  bf16* emb2_b = (bf16*)(w + so); so += 51 * 128 * 2 + 256;
  float* als1 = (float*)(w + so); so += NN * 4 * 4;
  float* ald1 = (float*)(w + so); so += NN * 4 * 4;
  float* als2 = (float*)(w + so); so += NN * 4;
  float* ald2 = (float*)(w + so); so += NN * 4;
  float* aw1 = (float*)(w + so); so += EE * 4 * 4;   // 4 MB
  float* selfw1 = (float*)(w + so); so += NN * 4 * 4;
  float* inv1 = (float*)(w + so); so += NN * 4 * 4;
  float* aw2 = (float*)(w + so); so += EE * 4;       // 1 MB
  float* selfw2 = (float*)(w + so); so += NN * 4;
  float* inv2 = (float*)(w + so); so += NN * 4;
  float* ws1 = (float*)(w + so); so += 512 * 4;
  float* wd1 = (float*)(w + so); so += 512 * 4;
  int* indeg = (int*)(w + so); so += NN * 4;
  int* csroff = (int*)(w + so); so += (NN + 1) * 4 + 252;
  int* cursor = (int*)(w + so); so += NN * 4;
  int* esrc = (int*)(w + so); so += EE * 4;
  s8v* Bp1 = (s8v*)(w + so); so += 32 * 4 * 64 * 16;
  s8v* Bp2 = (s8v*)(w + so); so += 8 * 16 * 64 * 16;
  s8v* BpWv = (s8v*)(w + so); so += 8 * 24 * 64 * 16;
  s8v* BpWt = (s8v*)(w + so); so += 8 * 24 * 64 * 16;
  s8v* BpWs = (s8v*)(w + so); so += 8 * 8 * 64 * 16;

  // ---- CSR build ----
  hipMemsetAsync(indeg, 0, NN * 4, stream);
  hist_kernel<<<EE / 256, 256, 0, stream>>>(e_dst, indeg);
  scan_kernel<<<1, 1024, 0, stream>>>(indeg, csroff, cursor);
  fill_kernel<<<EE / 256, 256, 0, stream>>>(e_src, e_dst, cursor, esrc);

  // pack weights + convert t,v + fold conv1 score vectors
  packall_kernel<<<176, 256, 0, stream>>>(W1, Bp1, W2, Bp2, Wv, BpWv, Wt, BpWt, Wstart, BpWs);
  cvtpk2_kernel<<<1536, 256, 0, stream>>>((const float2*)t, (unsigned*)t_b,
                                          (const float2*)v, (unsigned*)v_b, 512 * 384);
  fold1_kernel<<<2, 256, 0, stream>>>(W1, a_src1, a_dst1, ws1, wd1);

  // emb2 (tiny), bf16 out
  sgemm_kernel<bf16><<<(51 * 128 + 63) / 64, 256, 0, stream>>>(emb, Wnode, bnode, emb2_b, 51, 128, 128, 128, 0);

  // ve+te merged, then start, via MFMA
  gemm_mfma_vt<<<dim3(2, 16), 256, 0, stream>>>((const short*)v_b, BpWv, bv,
                                                (const short*)t_b, BpWt, bt, (short*)vt_b);
  gemm_mfma<<<dim3(2, 8), 256, 0, stream>>>((const short*)vt_b, BpWs, bstart, (short*)start_b, 512, 128, 256, 128);

  // fused LN + conv1 scores
  ln_al1_wave<<<NN / 4, 256, 0, stream>>>((const unsigned*)start_b, (const unsigned*)emb2_b,
                                          m_idx, ln_g, ln_b, ws1, wd1, (unsigned*)x0b, als1, ald1);
  alpha1_kernel<<<NN * 4 / 256, 256, 0, stream>>>(als1, ald1, csroff, esrc, aw1, selfw1, inv1);

  // conv1 aggregation (high occupancy), then fused head-GEMM + ELU + conv2 GEMM + al2
  agg1y_kernel<<<(int)(((long)NN * 16 + 255) / 256), 256, 0, stream>>>(
      (const uint4*)x0b, (const float4*)aw1, (const float4*)selfw1, (const float4*)inv1,
      csroff, esrc, (uint4*)y1);
  conv12_kernel<<<dim3(1, NN / 64), 256, 0, stream>>>((const short*)y1, Bp1, b1, Bp2,
                                                      a_src2, a_dst2, (short*)xp2b, als2, ald2);

  alpha2_kernel<<<NN / 256, 256, 0, stream>>>(als2, ald2, csroff, esrc, aw2, selfw2, inv2);
  agg2w_kernel<<<(int)(((long)NN * 16 + 255) / 256), 256, 0, stream>>>(
      (const uint4*)xp2b, aw2, selfw2, inv2, csroff, esrc, b2, (uint4*)x2b);

  // fused pool + h1 + head (x2 bf16)
  tail_kernel<<<GG, 128, 0, stream>>>((const unsigned short*)x2b, m_idx, Wo1, bo1, Wo2, bo2, out);
}